// Round 2
// baseline (380.997 us; speedup 1.0000x reference)
//
#include <hip/hip_runtime.h>

// MiniRocket on MI355X.
// Fixed problem: N=256 samples, L=1024, 84 kernels (C(9,3) taps), 9996 features,
// 25 dilations (precomputed from _fit_dilations replication), f per dilation below.
//
// Pipeline:
//   1. mr_transpose: x (256,1024) -> xT (1024,256)   [lane = sample coalescing]
//   2. mr_main: per-wave (dil, 12-kernel group, 4-bias split, 64-sample chunk,
//      1/16 t-slice) -> per-lane register counters -> atomicAdd into u32 outT(9996,256)
//   3. mr_finalize: scale by 1/T (padded vs cropped) + transpose -> out(256,9996)
//
// Roofline note: 2.62G compares x 2 VALU + 2.82G C-ops + ~1G taps = ~9.4G lane-ops
// / 78.6 T lane-ops/s ~= 120 us VALU-bound. Workspace needed: ~10.75 MiB.

namespace {

constexpr int LSER = 1024;   // series length
constexpr int NS   = 256;    // samples
constexpr int NFEAT = 9996;
constexpr int NDIL = 25;
constexpr int GK   = 12;     // kernels per work item (84/12 = 7 groups)
constexpr int TSPLIT = 16;   // t-slices
constexpr int TCH  = LSER / TSPLIT;  // 64
constexpr int NBLOCKS_MAIN = 14336;

// dilations (sorted unique of logspace(0, log2(1023/8), 32, base=2).astype(int32))
__constant__ int c_DIL[NDIL] = {1,2,3,4,5,6,7,8,10,12,14,16,19,22,26,31,36,42,50,58,68,79,93,109,127};
// features-per-kernel per dilation (counts*119/32 floor + remainder distribution)
__constant__ int c_F[NDIL]   = {19,12,4,8,4,4,4,4,4,4,4,4,4,4,4,4,4,3,3,3,3,3,3,3,3};
// cumulative feature column offsets: FOFF[di] = sum_{<di} 84*F
__constant__ int c_FOFF[NDIL + 1] = {
    0,1596,2604,2940,3612,3948,4284,4620,4956,5292,5628,5964,6300,6636,6972,
    7308,7644,7980,8232,8484,8736,8988,9240,9492,9744,9996};
// block-id start per dilation; blocks per dilation = ceil(F/4) splits * 7 groups * 4 chunks * 16 tslices
__constant__ int c_ISTART[NDIL + 1] = {
    0,2240,3584,4032,4928,5376,5824,6272,6720,7168,7616,8064,8512,8960,9408,
    9856,10304,10752,11200,11648,12096,12544,12992,13440,13888,14336};

// combinations(range(9), 3) in lexicographic order — the MiniRocket +2 tap positions
constexpr int CIDX[84][3] = {
    {0,1,2},{0,1,3},{0,1,4},{0,1,5},{0,1,6},{0,1,7},{0,1,8},
    {0,2,3},{0,2,4},{0,2,5},{0,2,6},{0,2,7},{0,2,8},
    {0,3,4},{0,3,5},{0,3,6},{0,3,7},{0,3,8},
    {0,4,5},{0,4,6},{0,4,7},{0,4,8},
    {0,5,6},{0,5,7},{0,5,8},
    {0,6,7},{0,6,8},
    {0,7,8},
    {1,2,3},{1,2,4},{1,2,5},{1,2,6},{1,2,7},{1,2,8},
    {1,3,4},{1,3,5},{1,3,6},{1,3,7},{1,3,8},
    {1,4,5},{1,4,6},{1,4,7},{1,4,8},
    {1,5,6},{1,5,7},{1,5,8},
    {1,6,7},{1,6,8},
    {1,7,8},
    {2,3,4},{2,3,5},{2,3,6},{2,3,7},{2,3,8},
    {2,4,5},{2,4,6},{2,4,7},{2,4,8},
    {2,5,6},{2,5,7},{2,5,8},
    {2,6,7},{2,6,8},
    {2,7,8},
    {3,4,5},{3,4,6},{3,4,7},{3,4,8},
    {3,5,6},{3,5,7},{3,5,8},
    {3,6,7},{3,6,8},
    {3,7,8},
    {4,5,6},{4,5,7},{4,5,8},
    {4,6,7},{4,6,8},
    {4,7,8},
    {5,6,7},{5,6,8},
    {5,7,8},
    {6,7,8}};

__device__ __forceinline__ int imin(int a, int b) { return a < b ? a : b; }
__device__ __forceinline__ int imax(int a, int b) { return a > b ? a : b; }

// ---- compile-time unrolled per-kernel work (KK is a template constant so that
// s[CIDX[...]] indexing is always a literal register index, never scratch) ----
template <int K0, int FS, int PSEL, int KK>
__device__ __forceinline__ void do_kernels(const float (&s)[9], float sum,
                                           const float (&bv)[GK][FS],
                                           int (&cnt)[GK][FS]) {
  if constexpr (KK < GK) {
    // PSEL < 0: middle segment, all kernels. PSEL 0/1: padded-only segment,
    // process kernel iff (di + k) even i.e. (k & 1) == (di & 1) == PSEL.
    if constexpr (PSEL < 0 || (((K0 + KK) & 1) == PSEL)) {
      constexpr int ia = CIDX[K0 + KK][0];
      constexpr int ib = CIDX[K0 + KK][1];
      constexpr int ic = CIDX[K0 + KK][2];
      // match reference op order: 3.0 * (s[a]+s[b]+s[c]) - sum, no FMA contraction
      float s3 = (s[ia] + s[ib]) + s[ic];
      float cv = __fsub_rn(__fmul_rn(3.0f, s3), sum);
#pragma unroll
      for (int j = 0; j < FS; ++j) cnt[KK][j] += (cv > bv[KK][j]) ? 1 : 0;
    }
    do_kernels<K0, FS, PSEL, KK + 1>(s, sum, bv, cnt);
  }
}

template <int K0, int FS, int KK>
__device__ __forceinline__ void init_k(const float* __restrict__ biases,
                                       int colbase, int FTOT, int jb,
                                       float (&bv)[GK][FS], int (&cnt)[GK][FS]) {
  if constexpr (KK < GK) {
    const int cb = colbase + (K0 + KK) * FTOT + jb;
#pragma unroll
    for (int j = 0; j < FS; ++j) {
      bv[KK][j] = biases[cb + j];  // uniform -> s_load
      cnt[KK][j] = 0;
    }
    init_k<K0, FS, KK + 1>(biases, colbase, FTOT, jb, bv, cnt);
  }
}

template <int K0, int FS, int KK>
__device__ __forceinline__ void write_k(unsigned* __restrict__ outT, int colbase,
                                        int FTOT, int jb, int n,
                                        const int (&cnt)[GK][FS]) {
  if constexpr (KK < GK) {
    const int cb = colbase + (K0 + KK) * FTOT + jb;
#pragma unroll
    for (int j = 0; j < FS; ++j) {
      atomicAdd(&outT[(cb + j) * NS + n], (unsigned)cnt[KK][j]);  // coalesced per wave
    }
    write_k<K0, FS, KK + 1>(outT, colbase, FTOT, jb, n, cnt);
  }
}

// one t-range segment. PSEL >= 0 => bounds-checked taps + padded-parity kernels only.
template <int K0, int FS, int PSEL>
__device__ __forceinline__ void run_seg(int tlo, int thi, int d,
                                        const float* __restrict__ xb,
                                        const float (&bv)[GK][FS],
                                        int (&cnt)[GK][FS]) {
  for (int t = tlo; t < thi; ++t) {
    float s[9];
#pragma unroll
    for (int j = 0; j < 9; ++j) {
      const int r = t + (j - 4) * d;
      if constexpr (PSEL >= 0) {
        s[j] = (r >= 0 && r < LSER) ? xb[r * NS] : 0.0f;  // uniform condition
      } else {
        s[j] = xb[r * NS];
      }
    }
    // sequential left-fold sum, matching the reference's 9-element reduce order
    float sum = s[0];
#pragma unroll
    for (int j = 1; j < 9; ++j) sum += s[j];
    do_kernels<K0, FS, PSEL, 0>(s, sum, bv, cnt);
  }
}

template <int K0, int FS>
__device__ __forceinline__ void body(const float* __restrict__ xT,
                                     const float* __restrict__ biases,
                                     unsigned* __restrict__ outT, int d, int par,
                                     int FTOT, int jb, int colbase, int nc, int ts) {
  const int lane = (int)threadIdx.x;  // 0..63
  const int n = (nc << 6) + lane;
  const float* xb = xT + n;  // row r of this sample's column at xb[r*256]

  float bv[GK][FS];
  int cnt[GK][FS];
  init_k<K0, FS, 0>(biases, colbase, FTOT, jb, bv, cnt);

  const int p = 4 * d;
  const int t0 = ts * TCH, t1 = t0 + TCH;
  // [0,p) and [L-p,L): padded kernels only, taps need bounds checks.
  // [p,L-p): all kernels, taps always in-bounds. Regions partition [0,L).
  const int aHi = imin(t1, p);
  const int bLo = imax(t0, p), bHi = imin(t1, LSER - p);
  const int cLo = imax(t0, LSER - p);

  if (par == 0) {
    run_seg<K0, FS, 0>(t0, aHi, d, xb, bv, cnt);
  } else {
    run_seg<K0, FS, 1>(t0, aHi, d, xb, bv, cnt);
  }
  run_seg<K0, FS, -1>(bLo, bHi, d, xb, bv, cnt);
  if (par == 0) {
    run_seg<K0, FS, 0>(cLo, t1, d, xb, bv, cnt);
  } else {
    run_seg<K0, FS, 1>(cLo, t1, d, xb, bv, cnt);
  }

  write_k<K0, FS, 0>(outT, colbase, FTOT, jb, n, cnt);
}

}  // namespace

// ---------------------------------------------------------------------------

__global__ __launch_bounds__(256) void mr_transpose(const float* __restrict__ x,
                                                    float* __restrict__ xT) {
  __shared__ float tile[32][33];
  const int t0 = blockIdx.x << 5;
  const int n0 = blockIdx.y << 5;
  const int tx = threadIdx.x & 31, ty = threadIdx.x >> 5;  // 32 x 8
#pragma unroll
  for (int i = 0; i < 32; i += 8)
    tile[ty + i][tx] = x[(n0 + ty + i) * LSER + t0 + tx];
  __syncthreads();
#pragma unroll
  for (int i = 0; i < 32; i += 8)
    xT[(t0 + ty + i) * NS + n0 + tx] = tile[tx][ty + i];
}

__global__ __launch_bounds__(64) void mr_main(const float* __restrict__ xT,
                                              const float* __restrict__ biases,
                                              unsigned* __restrict__ outT) {
  const int bid = (int)blockIdx.x;
  int di = 0;
#pragma unroll 1
  while (di < NDIL - 1 && bid >= c_ISTART[di + 1]) ++di;
  const int rel = bid - c_ISTART[di];
  const int split = rel / 448;          // which 4-wide bias split
  const int r2 = rel - split * 448;
  const int g = r2 >> 6;                // kernel group 0..6
  const int r3 = r2 & 63;
  const int nc = r3 >> 4;               // sample chunk 0..3
  const int ts = r3 & 15;               // t-slice 0..15
  const int d = c_DIL[di];
  const int FTOT = c_F[di];
  const int colbase = c_FOFF[di];
  const int par = di & 1;
  const int jb = split << 2;
  const int FS = imin(4, FTOT - jb);

  if (FS == 4) {
    switch (g) {
      case 0: body<0, 4>(xT, biases, outT, d, par, FTOT, jb, colbase, nc, ts); break;
      case 1: body<12, 4>(xT, biases, outT, d, par, FTOT, jb, colbase, nc, ts); break;
      case 2: body<24, 4>(xT, biases, outT, d, par, FTOT, jb, colbase, nc, ts); break;
      case 3: body<36, 4>(xT, biases, outT, d, par, FTOT, jb, colbase, nc, ts); break;
      case 4: body<48, 4>(xT, biases, outT, d, par, FTOT, jb, colbase, nc, ts); break;
      case 5: body<60, 4>(xT, biases, outT, d, par, FTOT, jb, colbase, nc, ts); break;
      default: body<72, 4>(xT, biases, outT, d, par, FTOT, jb, colbase, nc, ts); break;
    }
  } else {  // FS == 3
    switch (g) {
      case 0: body<0, 3>(xT, biases, outT, d, par, FTOT, jb, colbase, nc, ts); break;
      case 1: body<12, 3>(xT, biases, outT, d, par, FTOT, jb, colbase, nc, ts); break;
      case 2: body<24, 3>(xT, biases, outT, d, par, FTOT, jb, colbase, nc, ts); break;
      case 3: body<36, 3>(xT, biases, outT, d, par, FTOT, jb, colbase, nc, ts); break;
      case 4: body<48, 3>(xT, biases, outT, d, par, FTOT, jb, colbase, nc, ts); break;
      case 5: body<60, 3>(xT, biases, outT, d, par, FTOT, jb, colbase, nc, ts); break;
      default: body<72, 3>(xT, biases, outT, d, par, FTOT, jb, colbase, nc, ts); break;
    }
  }
}

__global__ __launch_bounds__(256) void mr_finalize(const unsigned* __restrict__ outT,
                                                   float* __restrict__ out) {
  __shared__ unsigned tile[64][65];
  __shared__ float sscale[64];
  const int tb = (int)blockIdx.x;  // 0..627  (157 col-tiles x 4 n-tiles)
  const int ct = tb % 157, nt = tb / 157;
  const int c0 = ct << 6, n0 = nt << 6;
  const int tid = (int)threadIdx.x;

  if (tid < 64) {
    const int col = c0 + tid;
    float sc = 0.0f;
    if (col < NFEAT) {
      int di = 0;
      while (di < NDIL - 1 && col >= c_FOFF[di + 1]) ++di;
      const int rel = col - c_FOFF[di];
      const int f = c_F[di];
      const int k = rel / f;
      const int d = c_DIL[di];
      const bool padded = (((di + k) & 1) == 0);
      const int T = padded ? LSER : (LSER - 8 * d);
      sc = 1.0f / (float)T;
    }
    sscale[tid] = sc;
  }
#pragma unroll
  for (int i = 0; i < 16; ++i) {
    const int lin = tid + (i << 8);
    const int dc = lin >> 6, dn = lin & 63;
    const int col = c0 + dc;
    tile[dc][dn] = (col < NFEAT) ? outT[col * NS + n0 + dn] : 0u;
  }
  __syncthreads();
#pragma unroll
  for (int i = 0; i < 16; ++i) {
    const int lin = tid + (i << 8);
    const int dn = lin >> 6, dc = lin & 63;
    const int col = c0 + dc;
    if (col < NFEAT)
      out[(n0 + dn) * NFEAT + col] = (float)tile[dc][dn] * sscale[dc];
  }
}

extern "C" void kernel_launch(void* const* d_in, const int* in_sizes, int n_in,
                              void* d_out, int out_size, void* d_ws, size_t ws_size,
                              hipStream_t stream) {
  (void)in_sizes; (void)n_in; (void)out_size; (void)ws_size;
  const float* x = (const float*)d_in[0];        // (256, 1, 1024) f32
  const float* biases = (const float*)d_in[1];   // (9996,) f32
  float* out = (float*)d_out;                    // (256, 9996) f32

  float* xT = (float*)d_ws;                                       // 1 MiB
  unsigned* outT = (unsigned*)((char*)d_ws + (size_t)(1 << 20));  // 9996*256*4 B

  hipMemsetAsync(outT, 0, (size_t)NFEAT * NS * sizeof(unsigned), stream);
  hipLaunchKernelGGL(mr_transpose, dim3(32, 8), dim3(256), 0, stream, x, xT);
  hipLaunchKernelGGL(mr_main, dim3(NBLOCKS_MAIN), dim3(64), 0, stream, xT, biases, outT);
  hipLaunchKernelGGL(mr_finalize, dim3(628), dim3(256), 0, stream, outT, out);
}